// Round 6
// baseline (336.312 us; speedup 1.0000x reference)
//
#include <hip/hip_runtime.h>
#include <hip/hip_bf16.h>

// out[b,o] = sum_n relu( (s[b]-v[n]) . W[n,o,:] + bias[n,o] )
//          = sum_n relu( s[b].W[n,o,:] + c[n,o] ),  c[n,o] = bias[n,o] - v[n].W[n,o,:]
//
// Path A (full ws):
//   sb_kernel:   Sb = bf16(S)                       (1 MiB)
//   prep_kernel: Wb = bf16(W), c = bias - v.W       (128 MiB + 512 KiB)
//   main_kernel: BM=64 x BO=64, TPB=256 (4 waves), n split across 2 blocks
//     -> grid 1024, ~150 regs -> 3 blocks/CU = 3 waves/SIMD.
//     A-tile staged in K-chunks (128 k, 16 KiB) double-buffered via
//     global_load_lds(16B) with inverse-swizzled SOURCE (LDS dest linear,
//     reads XOR-swizzled -> ~2-way conflicts). Partial n-sums combined with
//     atomicAdd (2 addends -> exact); d_out zeroed via hipMemsetAsync.
// Path B (ws >= Wb+c): round-3 proven kernel (157 us).
// Path C: fused fp32-W kernel.

typedef __attribute__((ext_vector_type(8))) short  bf16x8;
typedef __attribute__((ext_vector_type(4))) short  bf16x4;
typedef __attribute__((ext_vector_type(4))) float  f32x4;

constexpr int B   = 1024;
constexpr int N   = 64;
constexpr int D   = 512;
constexpr int OUT = 2048;

constexpr int BM  = 64;     // rows per block (path A)
constexpr int BO  = 64;     // cols per block; 4 waves x 16 cols
constexpr int TPB = 256;    // 4 waves

static __device__ __forceinline__ unsigned short f2bf(float f) {
    unsigned int u = __builtin_bit_cast(unsigned int, f);
    u += 0x7FFFu + ((u >> 16) & 1u);
    return (unsigned short)(u >> 16);
}

static __device__ __forceinline__ bf16x4 cvt4(float4 a) {
    bf16x4 r;
    r[0] = (short)f2bf(a.x); r[1] = (short)f2bf(a.y);
    r[2] = (short)f2bf(a.z); r[3] = (short)f2bf(a.w);
    return r;
}

static __device__ __forceinline__ bf16x8 cvt8(float4 a, float4 b) {
    bf16x8 r;
    r[0] = (short)f2bf(a.x); r[1] = (short)f2bf(a.y);
    r[2] = (short)f2bf(a.z); r[3] = (short)f2bf(a.w);
    r[4] = (short)f2bf(b.x); r[5] = (short)f2bf(b.y);
    r[6] = (short)f2bf(b.z); r[7] = (short)f2bf(b.w);
    return r;
}

// ---------------- sb: Sb = bf16(S), plain [B, D] ----------------
__global__ __launch_bounds__(256) void sb_kernel(const float* __restrict__ S,
                                                 unsigned short* __restrict__ Sb) {
    const int idx = blockIdx.x * 256 + threadIdx.x;   // 8 elems each
    const float4* sp = reinterpret_cast<const float4*>(S + (size_t)idx * 8);
    *reinterpret_cast<bf16x8*>(Sb + (size_t)idx * 8) = cvt8(sp[0], sp[1]);
}

// ---------------- prep: Wb = bf16(W); c = bias - v.W ----------------
__global__ __launch_bounds__(256) void prep_kernel(const float* __restrict__ W,
                                                   const float* __restrict__ V,
                                                   const float* __restrict__ bias,
                                                   unsigned short* __restrict__ Wb,
                                                   float* __restrict__ c) {
    const int wid  = (blockIdx.x * 256 + threadIdx.x) >> 6;   // row id = n*OUT + o
    const int lane = threadIdx.x & 63;
    const int n = wid >> 11;          // / OUT

    const size_t rbase = (size_t)wid * D;
    float4 w0 = *reinterpret_cast<const float4*>(W + rbase + lane * 4);
    float4 w1 = *reinterpret_cast<const float4*>(W + rbase + 256 + lane * 4);
    float4 v0 = *reinterpret_cast<const float4*>(V + (size_t)n * D + lane * 4);
    float4 v1 = *reinterpret_cast<const float4*>(V + (size_t)n * D + 256 + lane * 4);

    *reinterpret_cast<bf16x4*>(Wb + rbase + lane * 4)       = cvt4(w0);
    *reinterpret_cast<bf16x4*>(Wb + rbase + 256 + lane * 4) = cvt4(w1);

    float s = w0.x * v0.x + w0.y * v0.y + w0.z * v0.z + w0.w * v0.w
            + w1.x * v1.x + w1.y * v1.y + w1.z * v1.z + w1.w * v1.w;
    #pragma unroll
    for (int off = 1; off < 64; off <<= 1) s += __shfl_xor(s, off);
    if (lane == 0) c[wid] = bias[wid] - s;
}

// ---------------- Path A main: chunked-dbuf gload_lds GEMM ----------------
__global__ __launch_bounds__(TPB) void main_kernel(const unsigned short* __restrict__ Sb,
                                                   const unsigned short* __restrict__ Wb,
                                                   const float* __restrict__ C,
                                                   float* __restrict__ out) {
    // Per-chunk A-tile: 64 rows x 128 k bf16 = 16 KiB, double-buffered.
    __shared__ unsigned short As[2][BM * 128];   // 32 KiB

    // grid 1024: o_idx(0..31) = (bid&7)*4 + (bid>>8), b_idx = (bid>>3)&15,
    // ng = (bid>>7)&1.  Same-o blocks share an XCD (bid%8) for W L2 reuse.
    const int bid   = blockIdx.x;
    const int o_idx = (bid & 7) * 4 + (bid >> 8);
    const int b_idx = (bid >> 3) & 15;
    const int ng    = (bid >> 7) & 1;
    const int ob0   = o_idx * BO;
    const int bm0   = b_idx * BM;

    const int t    = threadIdx.x;
    const int lane = t & 63;
    const int w    = t >> 6;          // wave = o-group (16 cols)
    const int l15  = lane & 15;
    const int lg   = lane >> 4;       // 0..3
    const int l7   = l15 & 7;
    const int ocol = ob0 + w * 16 + l15;

    const unsigned short* sbase = Sb + (size_t)bm0 * D;

    // async-stage chunk ck into buffer bufi: LDS dest linear (HW pattern),
    // global src inverse-swizzled so reads at slot = kcc ^ (row&7) are correct.
    auto stage = [&](int bufi, int ck) {
        const unsigned short* cb = sbase + ck * 128;
        #pragma unroll
        for (int l = 0; l < 4; ++l) {
            const int idx  = l * 256 + t;       // 16B-chunk id, 0..1023
            const int row  = idx >> 4;          // 0..63
            const int slot = idx & 15;
            const unsigned short* src = cb + row * D + ((slot ^ (row & 7)) * 8);
            unsigned short* dst = &As[bufi][idx * 8];
            __builtin_amdgcn_global_load_lds(
                (const __attribute__((address_space(1))) void*)src,
                (__attribute__((address_space(3))) void*)dst, 16, 0, 0);
        }
    };

    f32x4 oacc[4];
    #pragma unroll
    for (int mi = 0; mi < 4; ++mi) oacc[mi] = (f32x4){0.f, 0.f, 0.f, 0.f};
    f32x4 pre[4][4];
    #pragma unroll
    for (int j = 0; j < 4; ++j)
        #pragma unroll
        for (int mi = 0; mi < 4; ++mi) pre[j][mi] = (f32x4){0.f, 0.f, 0.f, 0.f};

    stage(0, 0);
    __syncthreads();

    // 8 nc (4 branches each, this block's n-half) x 4 K-chunks = 32 iterations.
    constexpr int NIT = 32;
    #pragma unroll 2
    for (int it = 0; it < NIT; ++it) {
        const int nc  = it >> 2;
        const int ck  = it & 3;
        const int buf = it & 1;
        const int n0  = ng * 32 + nc * 4;

        if (it < NIT - 1) stage(buf ^ 1, (it + 1) & 3);

        const unsigned short* wbase = Wb + ((size_t)n0 * OUT + ocol) * D + lg * 8;
        const unsigned short* abase = &As[buf][0];

        #pragma unroll
        for (int ks = 0; ks < 4; ++ks) {
            const int kg = (ck * 4 + ks) * 32;          // k element offset
            bf16x8 bq0 = *reinterpret_cast<const bf16x8*>(wbase + 0 * (size_t)(OUT * D) + kg);
            bf16x8 bq1 = *reinterpret_cast<const bf16x8*>(wbase + 1 * (size_t)(OUT * D) + kg);
            bf16x8 bq2 = *reinterpret_cast<const bf16x8*>(wbase + 2 * (size_t)(OUT * D) + kg);
            bf16x8 bq3 = *reinterpret_cast<const bf16x8*>(wbase + 3 * (size_t)(OUT * D) + kg);
            const int kslot = (ks * 4 + lg) ^ l7;       // swizzled 16B slot
            #pragma unroll
            for (int mi = 0; mi < 4; ++mi) {
                const int row = mi * 16 + l15;
                bf16x8 aq = *reinterpret_cast<const bf16x8*>(abase + row * 128 + kslot * 8);
                pre[0][mi] = __builtin_amdgcn_mfma_f32_16x16x32_bf16(aq, bq0, pre[0][mi], 0, 0, 0);
                pre[1][mi] = __builtin_amdgcn_mfma_f32_16x16x32_bf16(aq, bq1, pre[1][mi], 0, 0, 0);
                pre[2][mi] = __builtin_amdgcn_mfma_f32_16x16x32_bf16(aq, bq2, pre[2][mi], 0, 0, 0);
                pre[3][mi] = __builtin_amdgcn_mfma_f32_16x16x32_bf16(aq, bq3, pre[3][mi], 0, 0, 0);
            }
        }

        if (ck == 3) {
            #pragma unroll
            for (int j = 0; j < 4; ++j) {
                const float cv = C[(n0 + j) * OUT + ocol];
                #pragma unroll
                for (int mi = 0; mi < 4; ++mi) {
                    #pragma unroll
                    for (int r = 0; r < 4; ++r) {
                        oacc[mi][r] += fmaxf(pre[j][mi][r] + cv, 0.f);
                        pre[j][mi][r] = 0.f;
                    }
                }
            }
        }
        __syncthreads();
    }

    // combine the two n-halves: exactly 2 addends per element -> exact.
    #pragma unroll
    for (int mi = 0; mi < 4; ++mi) {
        #pragma unroll
        for (int r = 0; r < 4; ++r) {
            const int row = bm0 + mi * 16 + lg * 4 + r;
            atomicAdd(&out[(size_t)row * OUT + ocol], oacc[mi][r]);
        }
    }
}

// ---------------- Path B: round-3 proven main (BM=128, 8 waves) ----------------
__global__ __launch_bounds__(512) void main_r3(const float* __restrict__ S,
                                               const unsigned short* __restrict__ Wb,
                                               const float* __restrict__ C,
                                               float* __restrict__ out) {
    __shared__ unsigned short As3[128 * D];   // 128 KiB

    const int t    = threadIdx.x;
    const int lane = t & 63;
    const int w    = t >> 6;
    const int og   = w & 3;
    const int ngh  = w >> 2;
    const int l15  = lane & 15;
    const int lg   = lane >> 4;
    const int ob0  = blockIdx.x * 64;
    const int bm0  = blockIdx.y * 128;
    const int ocol = ob0 + og * 16 + l15;

    #pragma unroll
    for (int i = 0; i < (128 * D / 8) / 512; ++i) {
        int cid = i * 512 + t;
        int row = cid >> 6;
        int kc  = cid & 63;
        const float4* sp = reinterpret_cast<const float4*>(S + (size_t)(bm0 + row) * D + kc * 8);
        bf16x8 val = cvt8(sp[0], sp[1]);
        *reinterpret_cast<bf16x8*>(&As3[row * D + ((kc ^ (row & 7)) * 8)]) = val;
    }
    __syncthreads();

    f32x4 oacc[8];
    #pragma unroll
    for (int mi = 0; mi < 8; ++mi) oacc[mi] = (f32x4){0.f, 0.f, 0.f, 0.f};

    const int kofs = lg * 8;

    for (int nc = 0; nc < 8; ++nc) {
        const int n0 = ngh * 32 + nc * 4;

        f32x4 pre[4][8];
        #pragma unroll
        for (int j = 0; j < 4; ++j)
            #pragma unroll
            for (int mi = 0; mi < 8; ++mi) pre[j][mi] = (f32x4){0.f, 0.f, 0.f, 0.f};

        const unsigned short* wbase = Wb + ((size_t)n0 * OUT + ocol) * D + kofs;

        #pragma unroll 2
        for (int ks = 0; ks < 16; ++ks) {
            bf16x8 bq[4];
            #pragma unroll
            for (int j = 0; j < 4; ++j)
                bq[j] = *reinterpret_cast<const bf16x8*>(wbase + (size_t)j * (OUT * D) + ks * 32);

            const int kc = ks * 4 + lg;
            #pragma unroll
            for (int mi = 0; mi < 8; ++mi) {
                const int row = mi * 16 + l15;
                bf16x8 aq = *reinterpret_cast<const bf16x8*>(
                    &As3[row * D + ((kc ^ (row & 7)) * 8)]);
                pre[0][mi] = __builtin_amdgcn_mfma_f32_16x16x32_bf16(aq, bq[0], pre[0][mi], 0, 0, 0);
                pre[1][mi] = __builtin_amdgcn_mfma_f32_16x16x32_bf16(aq, bq[1], pre[1][mi], 0, 0, 0);
                pre[2][mi] = __builtin_amdgcn_mfma_f32_16x16x32_bf16(aq, bq[2], pre[2][mi], 0, 0, 0);
                pre[3][mi] = __builtin_amdgcn_mfma_f32_16x16x32_bf16(aq, bq[3], pre[3][mi], 0, 0, 0);
            }
        }

        #pragma unroll
        for (int j = 0; j < 4; ++j) {
            const float cv = C[(n0 + j) * OUT + ocol];
            #pragma unroll
            for (int mi = 0; mi < 8; ++mi)
                #pragma unroll
                for (int r = 0; r < 4; ++r)
                    oacc[mi][r] += fmaxf(pre[j][mi][r] + cv, 0.f);
        }
    }

    __syncthreads();
    float* red = reinterpret_cast<float*>(As3);
    if (ngh == 1) {
        #pragma unroll
        for (int mi = 0; mi < 8; ++mi)
            *reinterpret_cast<f32x4*>(&red[(og * 8 + mi) * 256 + lane * 4]) = oacc[mi];
    }
    __syncthreads();
    if (ngh == 0) {
        #pragma unroll
        for (int mi = 0; mi < 8; ++mi) {
            f32x4 o2 = *reinterpret_cast<const f32x4*>(&red[(og * 8 + mi) * 256 + lane * 4]);
            #pragma unroll
            for (int r = 0; r < 4; ++r) {
                int row = bm0 + mi * 16 + lg * 4 + r;
                out[(size_t)row * OUT + ocol] = oacc[mi][r] + o2[r];
            }
        }
    }
}

// ---------------- Path C: fused fp32-W fallback ----------------
__global__ __launch_bounds__(512) void fused_kernel(const float* __restrict__ S,
                                                    const float* __restrict__ W,
                                                    const float* __restrict__ V,
                                                    const float* __restrict__ bias,
                                                    float* __restrict__ out) {
    __shared__ unsigned short As3[128 * D];

    const int t    = threadIdx.x;
    const int lane = t & 63;
    const int w    = t >> 6;
    const int og   = w & 3;
    const int ngh  = w >> 2;
    const int l15  = lane & 15;
    const int lg   = lane >> 4;
    const int ob0  = blockIdx.x * 64;
    const int bm0  = blockIdx.y * 128;
    const int ocol = ob0 + og * 16 + l15;

    #pragma unroll
    for (int i = 0; i < (128 * D / 8) / 512; ++i) {
        int cid = i * 512 + t;
        int row = cid >> 6;
        int kc  = cid & 63;
        const float4* sp = reinterpret_cast<const float4*>(S + (size_t)(bm0 + row) * D + kc * 8);
        bf16x8 val = cvt8(sp[0], sp[1]);
        *reinterpret_cast<bf16x8*>(&As3[row * D + ((kc ^ (row & 7)) * 8)]) = val;
    }
    __syncthreads();

    f32x4 oacc[8];
    #pragma unroll
    for (int mi = 0; mi < 8; ++mi) oacc[mi] = (f32x4){0.f, 0.f, 0.f, 0.f};

    const int kofs = lg * 8;

    for (int nc = 0; nc < 8; ++nc) {
        const int n0 = ngh * 32 + nc * 4;

        f32x4 pre[4][8];
        #pragma unroll
        for (int j = 0; j < 4; ++j)
            #pragma unroll
            for (int mi = 0; mi < 8; ++mi) pre[j][mi] = (f32x4){0.f, 0.f, 0.f, 0.f};

        float cacc[4] = {0.f, 0.f, 0.f, 0.f};

        const float* wbase = W + ((size_t)n0 * OUT + ocol) * D + kofs;
        const float* vbase = V + (size_t)n0 * D + kofs;

        #pragma unroll 2
        for (int ks = 0; ks < 16; ++ks) {
            bf16x8 bq[4];
            #pragma unroll
            for (int j = 0; j < 4; ++j) {
                const float* wr = wbase + (size_t)j * (OUT * D) + ks * 32;
                float4 wa = *reinterpret_cast<const float4*>(wr);
                float4 wb = *reinterpret_cast<const float4*>(wr + 4);
                const float* vr = vbase + (size_t)j * D + ks * 32;
                float4 va = *reinterpret_cast<const float4*>(vr);
                float4 vb = *reinterpret_cast<const float4*>(vr + 4);
                cacc[j] += wa.x * va.x + wa.y * va.y + wa.z * va.z + wa.w * va.w
                         + wb.x * vb.x + wb.y * vb.y + wb.z * vb.z + wb.w * vb.w;
                bq[j] = cvt8(wa, wb);
            }
            const int kc = ks * 4 + lg;
            #pragma unroll
            for (int mi = 0; mi < 8; ++mi) {
                const int row = mi * 16 + l15;
                bf16x8 aq = *reinterpret_cast<const bf16x8*>(
                    &As3[row * D + ((kc ^ (row & 7)) * 8)]);
                pre[0][mi] = __builtin_amdgcn_mfma_f32_16x16x32_bf16(aq, bq[0], pre[0][mi], 0, 0, 0);
                pre[1][mi] = __builtin_amdgcn_mfma_f32_16x16x32_bf16(aq, bq[1], pre[1][mi], 0, 0, 0);
                pre[2][mi] = __builtin_amdgcn_mfma_f32_16x16x32_bf16(aq, bq[2], pre[2][mi], 0, 0, 0);
                pre[3][mi] = __builtin_amdgcn_mfma_f32_16x16x32_bf16(aq, bq[3], pre[3][mi], 0, 0, 0);
            }
        }

        #pragma unroll
        for (int j = 0; j < 4; ++j) {
            float cs = cacc[j];
            cs += __shfl_xor(cs, 16);
            cs += __shfl_xor(cs, 32);
            const float cv = bias[(n0 + j) * OUT + ocol] - cs;
            #pragma unroll
            for (int mi = 0; mi < 8; ++mi)
                #pragma unroll
                for (int r = 0; r < 4; ++r)
                    oacc[mi][r] += fmaxf(pre[j][mi][r] + cv, 0.f);
        }
    }

    __syncthreads();
    float* red = reinterpret_cast<float*>(As3);
    if (ngh == 1) {
        #pragma unroll
        for (int mi = 0; mi < 8; ++mi)
            *reinterpret_cast<f32x4*>(&red[(og * 8 + mi) * 256 + lane * 4]) = oacc[mi];
    }
    __syncthreads();
    if (ngh == 0) {
        #pragma unroll
        for (int mi = 0; mi < 8; ++mi) {
            f32x4 o2 = *reinterpret_cast<const f32x4*>(&red[(og * 8 + mi) * 256 + lane * 4]);
            #pragma unroll
            for (int r = 0; r < 4; ++r) {
                int row = bm0 + mi * 16 + lg * 4 + r;
                out[(size_t)row * OUT + ocol] = oacc[mi][r] + o2[r];
            }
        }
    }
}

extern "C" void kernel_launch(void* const* d_in, const int* in_sizes, int n_in,
                              void* d_out, int out_size, void* d_ws, size_t ws_size,
                              hipStream_t stream) {
    const float* S    = (const float*)d_in[0];   // semantic_vec [B, D]
    const float* V    = (const float*)d_in[1];   // vertices     [N, D]
    const float* W    = (const float*)d_in[2];   // W            [N, OUT, D]
    const float* bias = (const float*)d_in[3];   // b            [N, OUT]
    float* out = (float*)d_out;                  // [B, OUT] f32

    const size_t wb_bytes = (size_t)N * OUT * D * sizeof(unsigned short); // 128 MiB
    const size_t c_bytes  = (size_t)N * OUT * sizeof(float);              // 512 KiB
    const size_t sb_bytes = (size_t)B * D * sizeof(unsigned short);       // 1 MiB

    if (ws_size >= wb_bytes + c_bytes + sb_bytes) {
        unsigned short* Wb = (unsigned short*)d_ws;
        float*          c  = (float*)((char*)d_ws + wb_bytes);
        unsigned short* Sb = (unsigned short*)((char*)d_ws + wb_bytes + c_bytes);
        sb_kernel<<<dim3(B * D / 8 / 256), dim3(256), 0, stream>>>(S, Sb);
        prep_kernel<<<dim3((N * OUT) / 4), dim3(256), 0, stream>>>(W, V, bias, Wb, c);
        hipMemsetAsync(d_out, 0, (size_t)out_size * sizeof(float), stream);
        main_kernel<<<dim3((OUT / BO) * (B / BM) * 2), dim3(TPB), 0, stream>>>(Sb, Wb, c, out);
    } else if (ws_size >= wb_bytes + c_bytes) {
        unsigned short* Wb = (unsigned short*)d_ws;
        float*          c  = (float*)((char*)d_ws + wb_bytes);
        prep_kernel<<<dim3((N * OUT) / 4), dim3(256), 0, stream>>>(W, V, bias, Wb, c);
        main_r3<<<dim3(OUT / 64, B / 128), dim3(512), 0, stream>>>(S, Wb, c, out);
    } else {
        fused_kernel<<<dim3(OUT / 64, B / 128), dim3(512), 0, stream>>>(S, W, V, bias, out);
    }
}

// Round 7
// 214.988 us; speedup vs baseline: 1.5643x; 1.5643x over previous
//
#include <hip/hip_runtime.h>
#include <hip/hip_bf16.h>

// out[b,o] = sum_n relu( (s[b]-v[n]) . W[n,o,:] + bias[n,o] )
//          = sum_n relu( s[b].W[n,o,:] + c[n,o] ),  c[n,o] = bias[n,o] - v[n].W[n,o,:]
//
// prep  (memory-bound): Wb = bf16(W), c = bias - v.W  (reads W once).
// main  (MFMA): 32x32x16 MFMA (2x FLOP per 16B operand read vs 16x16x32 --
//   r3's plateau was the LDS read pipe at ~100% after the compiler's j-loop
//   rotation made ds_reads 1:1 with MFMAs). BM=128 x BO=64, 8 waves =
//   2 og(32 cols) x 4 ng(16 n each). A staged once in LDS, XOR-swizzled
//   kc ^ (row&15) (2-way conflicts = free). W frags global->reg (L2-resident,
//   same-o blocks land on the same XCD). 4-way n-reduction via LDS tree.
// fused (fallback if ws too small): r2-proven fp32-W kernel.

typedef __attribute__((ext_vector_type(8)))  short bf16x8;
typedef __attribute__((ext_vector_type(4)))  short bf16x4;
typedef __attribute__((ext_vector_type(4)))  float f32x4;
typedef __attribute__((ext_vector_type(16))) float f32x16;

constexpr int B   = 1024;
constexpr int N   = 64;
constexpr int D   = 512;
constexpr int OUT = 2048;

constexpr int BM  = 128;    // rows per block
constexpr int BO  = 64;     // cols per block: 2 o-groups x 32
constexpr int TPB = 512;    // 8 waves

static __device__ __forceinline__ unsigned short f2bf(float f) {
    unsigned int u = __builtin_bit_cast(unsigned int, f);
    u += 0x7FFFu + ((u >> 16) & 1u);
    return (unsigned short)(u >> 16);
}

static __device__ __forceinline__ bf16x4 cvt4(float4 a) {
    bf16x4 r;
    r[0] = (short)f2bf(a.x); r[1] = (short)f2bf(a.y);
    r[2] = (short)f2bf(a.z); r[3] = (short)f2bf(a.w);
    return r;
}

static __device__ __forceinline__ bf16x8 cvt8(float4 a, float4 b) {
    bf16x8 r;
    r[0] = (short)f2bf(a.x); r[1] = (short)f2bf(a.y);
    r[2] = (short)f2bf(a.z); r[3] = (short)f2bf(a.w);
    r[4] = (short)f2bf(b.x); r[5] = (short)f2bf(b.y);
    r[6] = (short)f2bf(b.z); r[7] = (short)f2bf(b.w);
    return r;
}

// ---------------- prep: Wb = bf16(W); c = bias - v.W ----------------
__global__ __launch_bounds__(256) void prep_kernel(const float* __restrict__ W,
                                                   const float* __restrict__ V,
                                                   const float* __restrict__ bias,
                                                   unsigned short* __restrict__ Wb,
                                                   float* __restrict__ c) {
    const int wid  = (blockIdx.x * 256 + threadIdx.x) >> 6;   // row id = n*OUT + o
    const int lane = threadIdx.x & 63;
    const int n = wid >> 11;          // / OUT

    const size_t rbase = (size_t)wid * D;
    float4 w0 = *reinterpret_cast<const float4*>(W + rbase + lane * 4);
    float4 w1 = *reinterpret_cast<const float4*>(W + rbase + 256 + lane * 4);
    float4 v0 = *reinterpret_cast<const float4*>(V + (size_t)n * D + lane * 4);
    float4 v1 = *reinterpret_cast<const float4*>(V + (size_t)n * D + 256 + lane * 4);

    *reinterpret_cast<bf16x4*>(Wb + rbase + lane * 4)       = cvt4(w0);
    *reinterpret_cast<bf16x4*>(Wb + rbase + 256 + lane * 4) = cvt4(w1);

    float s = w0.x * v0.x + w0.y * v0.y + w0.z * v0.z + w0.w * v0.w
            + w1.x * v1.x + w1.y * v1.y + w1.z * v1.z + w1.w * v1.w;
    #pragma unroll
    for (int off = 1; off < 64; off <<= 1) s += __shfl_xor(s, off);
    if (lane == 0) c[wid] = bias[wid] - s;
}

// ---------------- main: 32x32x16 MFMA GEMM + relu + n-sum ----------------
__global__ __launch_bounds__(TPB) void main_kernel(const float* __restrict__ S,
                                                   const unsigned short* __restrict__ Wb,
                                                   const float* __restrict__ C,
                                                   float* __restrict__ out) {
    // A-tile: 128 rows x 512 k bf16, XOR-swizzled in 16B chunks: kc ^ (row&15)
    // (16 slots over 32-lane row groups -> 2-way bank aliasing = free).
    __shared__ unsigned short As[BM * D];   // 128 KiB

    const int t    = threadIdx.x;
    const int lane = t & 63;
    const int w    = t >> 6;          // 0..7
    const int og   = w & 1;           // o-group (32 cols)
    const int ng   = w >> 1;          // n-quarter (16 n each)
    const int oc   = lane & 31;
    const int hi   = lane >> 5;       // k-half selector (A and B)
    const int ob0  = blockIdx.x * BO;
    const int bm0  = blockIdx.y * BM;
    const int ocol = ob0 + og * 32 + oc;

    // ---- stage A = S[bm0:bm0+BM, :] as bf16 (once per block) ----
    #pragma unroll
    for (int i = 0; i < (BM * D / 8) / TPB; ++i) {   // 16 iters
        int cid = i * TPB + t;
        int row = cid >> 6;            // 64 chunks per row
        int kc  = cid & 63;
        const float4* sp = reinterpret_cast<const float4*>(S + (size_t)(bm0 + row) * D + kc * 8);
        bf16x8 val = cvt8(sp[0], sp[1]);
        *reinterpret_cast<bf16x8*>(&As[row * D + ((kc ^ (row & 15)) * 8)]) = val;
    }
    __syncthreads();

    f32x16 oacc[4];
    #pragma unroll
    for (int mi = 0; mi < 4; ++mi)
        #pragma unroll
        for (int r = 0; r < 16; ++r) oacc[mi][r] = 0.f;

    for (int nc = 0; nc < 8; ++nc) {
        const int n0 = ng * 16 + nc * 2;

        f32x16 pre[2][4];
        #pragma unroll
        for (int j = 0; j < 2; ++j)
            #pragma unroll
            for (int mi = 0; mi < 4; ++mi)
                #pragma unroll
                for (int r = 0; r < 16; ++r) pre[j][mi][r] = 0.f;

        const unsigned short* wb0 = Wb + ((size_t)n0 * OUT + ocol) * D + hi * 8;
        const unsigned short* wb1 = wb0 + (size_t)OUT * D;

        #pragma unroll 4
        for (int ks = 0; ks < 32; ++ks) {           // K-steps of 16
            bf16x8 bq0 = *reinterpret_cast<const bf16x8*>(wb0 + ks * 16);
            bf16x8 bq1 = *reinterpret_cast<const bf16x8*>(wb1 + ks * 16);
            const int kc2 = ks * 2 + hi;            // 16B chunk index along k
            #pragma unroll
            for (int mi = 0; mi < 4; ++mi) {
                const int row = mi * 32 + oc;       // A-frag row = lane&31
                bf16x8 aq = *reinterpret_cast<const bf16x8*>(
                    &As[row * D + ((kc2 ^ (row & 15)) * 8)]);
                pre[0][mi] = __builtin_amdgcn_mfma_f32_32x32x16_bf16(aq, bq0, pre[0][mi], 0, 0, 0);
                pre[1][mi] = __builtin_amdgcn_mfma_f32_32x32x16_bf16(aq, bq1, pre[1][mi], 0, 0, 0);
            }
        }

        #pragma unroll
        for (int j = 0; j < 2; ++j) {
            const float cv = C[(n0 + j) * OUT + ocol];
            #pragma unroll
            for (int mi = 0; mi < 4; ++mi)
                #pragma unroll
                for (int r = 0; r < 16; ++r)
                    oacc[mi][r] += fmaxf(pre[j][mi][r] + cv, 0.f);
        }
    }

    // ---- 4-way cross n-quarter reduction through LDS, then store ----
    // Slab per (ng-1, og): 4096 f32 (16 KiB); 6 slabs = 96 KiB. Writes/reads
    // are lane*16B contiguous -> conflict-free.
    __syncthreads();                      // everyone done reading As
    float* red = reinterpret_cast<float*>(As);
    if (ng != 0) {
        const int slab = ((ng - 1) * 2 + og) * 4096;
        #pragma unroll
        for (int mi = 0; mi < 4; ++mi) {
            #pragma unroll
            for (int rg = 0; rg < 4; ++rg) {
                f32x4 v = {oacc[mi][rg * 4 + 0], oacc[mi][rg * 4 + 1],
                           oacc[mi][rg * 4 + 2], oacc[mi][rg * 4 + 3]};
                *reinterpret_cast<f32x4*>(&red[slab + (mi * 4 + rg) * 256 + lane * 4]) = v;
            }
        }
    }
    __syncthreads();
    if (ng == 0) {
        #pragma unroll
        for (int mi = 0; mi < 4; ++mi) {
            #pragma unroll
            for (int rg = 0; rg < 4; ++rg) {
                f32x4 sum = {oacc[mi][rg * 4 + 0], oacc[mi][rg * 4 + 1],
                             oacc[mi][rg * 4 + 2], oacc[mi][rg * 4 + 3]};
                #pragma unroll
                for (int s = 0; s < 3; ++s) {
                    const int slab = (s * 2 + og) * 4096;
                    f32x4 o2 = *reinterpret_cast<const f32x4*>(
                        &red[slab + (mi * 4 + rg) * 256 + lane * 4]);
                    #pragma unroll
                    for (int q = 0; q < 4; ++q) sum[q] += o2[q];
                }
                // C/D layout (m74/m101): col = lane&31, row = (r&3)+8*(r>>2)+4*hi
                #pragma unroll
                for (int q = 0; q < 4; ++q) {
                    const int row = bm0 + mi * 32 + q + 8 * rg + 4 * hi;
                    out[(size_t)row * OUT + ocol] = sum[q];
                }
            }
        }
    }
}

// ---------------- fallback: fused fp32-W kernel (r2-proven) ----------------
__global__ __launch_bounds__(512) void fused_kernel(const float* __restrict__ S,
                                                    const float* __restrict__ W,
                                                    const float* __restrict__ V,
                                                    const float* __restrict__ bias,
                                                    float* __restrict__ out) {
    __shared__ unsigned short As3[128 * D];

    const int t    = threadIdx.x;
    const int lane = t & 63;
    const int w    = t >> 6;
    const int og   = w & 3;
    const int ngh  = w >> 2;
    const int l15  = lane & 15;
    const int lg   = lane >> 4;
    const int ob0  = blockIdx.x * 64;
    const int bm0  = blockIdx.y * 128;
    const int ocol = ob0 + og * 16 + l15;

    #pragma unroll
    for (int i = 0; i < (128 * D / 8) / 512; ++i) {
        int cid = i * 512 + t;
        int row = cid >> 6;
        int kc  = cid & 63;
        const float4* sp = reinterpret_cast<const float4*>(S + (size_t)(bm0 + row) * D + kc * 8);
        bf16x8 val = cvt8(sp[0], sp[1]);
        *reinterpret_cast<bf16x8*>(&As3[row * D + ((kc ^ (row & 7)) * 8)]) = val;
    }
    __syncthreads();

    f32x4 oacc[8];
    #pragma unroll
    for (int mi = 0; mi < 8; ++mi) oacc[mi] = (f32x4){0.f, 0.f, 0.f, 0.f};

    const int kofs = lg * 8;

    for (int nc = 0; nc < 8; ++nc) {
        const int n0 = ngh * 32 + nc * 4;

        f32x4 pre[4][8];
        #pragma unroll
        for (int j = 0; j < 4; ++j)
            #pragma unroll
            for (int mi = 0; mi < 8; ++mi) pre[j][mi] = (f32x4){0.f, 0.f, 0.f, 0.f};

        float cacc[4] = {0.f, 0.f, 0.f, 0.f};

        const float* wbase = W + ((size_t)n0 * OUT + ocol) * D + kofs;
        const float* vbase = V + (size_t)n0 * D + kofs;

        #pragma unroll 2
        for (int ks = 0; ks < 16; ++ks) {
            bf16x8 bq[4];
            #pragma unroll
            for (int j = 0; j < 4; ++j) {
                const float* wr = wbase + (size_t)j * (OUT * D) + ks * 32;
                float4 wa = *reinterpret_cast<const float4*>(wr);
                float4 wb = *reinterpret_cast<const float4*>(wr + 4);
                const float* vr = vbase + (size_t)j * D + ks * 32;
                float4 va = *reinterpret_cast<const float4*>(vr);
                float4 vb = *reinterpret_cast<const float4*>(vr + 4);
                cacc[j] += wa.x * va.x + wa.y * va.y + wa.z * va.z + wa.w * va.w
                         + wb.x * vb.x + wb.y * vb.y + wb.z * vb.z + wb.w * vb.w;
                bq[j] = cvt8(wa, wb);
            }
            const int kc = ks * 4 + lg;
            #pragma unroll
            for (int mi = 0; mi < 8; ++mi) {
                const int row = mi * 16 + l15;
                bf16x8 aq = *reinterpret_cast<const bf16x8*>(
                    &As3[row * D + ((kc ^ (row & 7)) * 8)]);
                pre[0][mi] = __builtin_amdgcn_mfma_f32_16x16x32_bf16(aq, bq[0], pre[0][mi], 0, 0, 0);
                pre[1][mi] = __builtin_amdgcn_mfma_f32_16x16x32_bf16(aq, bq[1], pre[1][mi], 0, 0, 0);
                pre[2][mi] = __builtin_amdgcn_mfma_f32_16x16x32_bf16(aq, bq[2], pre[2][mi], 0, 0, 0);
                pre[3][mi] = __builtin_amdgcn_mfma_f32_16x16x32_bf16(aq, bq[3], pre[3][mi], 0, 0, 0);
            }
        }

        #pragma unroll
        for (int j = 0; j < 4; ++j) {
            float cs = cacc[j];
            cs += __shfl_xor(cs, 16);
            cs += __shfl_xor(cs, 32);
            const float cv = bias[(n0 + j) * OUT + ocol] - cs;
            #pragma unroll
            for (int mi = 0; mi < 8; ++mi)
                #pragma unroll
                for (int r = 0; r < 4; ++r)
                    oacc[mi][r] += fmaxf(pre[j][mi][r] + cv, 0.f);
        }
    }

    __syncthreads();
    float* red = reinterpret_cast<float*>(As3);
    if (ngh == 1) {
        #pragma unroll
        for (int mi = 0; mi < 8; ++mi)
            *reinterpret_cast<f32x4*>(&red[(og * 8 + mi) * 256 + lane * 4]) = oacc[mi];
    }
    __syncthreads();
    if (ngh == 0) {
        #pragma unroll
        for (int mi = 0; mi < 8; ++mi) {
            f32x4 o2 = *reinterpret_cast<const f32x4*>(&red[(og * 8 + mi) * 256 + lane * 4]);
            #pragma unroll
            for (int r = 0; r < 4; ++r) {
                int row = bm0 + mi * 16 + lg * 4 + r;
                out[(size_t)row * OUT + ocol] = oacc[mi][r] + o2[r];
            }
        }
    }
}

extern "C" void kernel_launch(void* const* d_in, const int* in_sizes, int n_in,
                              void* d_out, int out_size, void* d_ws, size_t ws_size,
                              hipStream_t stream) {
    const float* S    = (const float*)d_in[0];   // semantic_vec [B, D]
    const float* V    = (const float*)d_in[1];   // vertices     [N, D]
    const float* W    = (const float*)d_in[2];   // W            [N, OUT, D]
    const float* bias = (const float*)d_in[3];   // b            [N, OUT]
    float* out = (float*)d_out;                  // [B, OUT] f32

    const size_t wb_bytes = (size_t)N * OUT * D * sizeof(unsigned short); // 128 MiB
    const size_t c_bytes  = (size_t)N * OUT * sizeof(float);              // 512 KiB

    if (ws_size >= wb_bytes + c_bytes) {
        unsigned short* Wb = (unsigned short*)d_ws;
        float*          c  = (float*)((char*)d_ws + wb_bytes);
        prep_kernel<<<dim3((N * OUT) / 4), dim3(256), 0, stream>>>(W, V, bias, Wb, c);
        main_kernel<<<dim3(OUT / BO, B / BM), dim3(TPB), 0, stream>>>(S, Wb, c, out);
    } else {
        fused_kernel<<<dim3(OUT / 64, B / 128), dim3(512), 0, stream>>>(S, W, V, bias, out);
    }
}